// Round 10
// baseline (207.342 us; speedup 1.0000x reference)
//
#include <hip/hip_runtime.h>

// GradientInputLayer: B=64, C=2, L=64, N=16, BIN=360//16=22, EPS=1e-5
// x: (64, 2*64^3) f32 in {0,1}; out: (64,2,16,16) f32
//
// ws layout: [0, 262144)      uint8 bin table tab[i*4096 + j*64 + k]
//            [262144, 393216) float g[128*256] accumulator (pair-major)
//
// R3: no device fences / nt loads per-block. R4: wave-privatization neutral.
// R5: pipelining neutral. R6: scatter ~38.8us even x-L3-hot (not BW-bound).
// R7: fewer flushes -3us. R8 diag: 4x compute => VALUBusy only 34%, HBM 9%
//   => stall-dominated. R9: branch-free slot RLE -1.8us, BUT slot[tid][10]
//   layout = 8-way LDS bank conflict on EVERY hot write (stride 80B,
//   20*8%32==0). R10: slot-major [s][tid] (conflict-free) + 2 channels per
//   block (p and p+64: shared bins/sqrt/cnt-chain, 9 loads/thread MLP,
//   4096 blocks).

#define BINS_PAD 80   // real bins are 0..68 (ax,az in 0..4); 69 = flush sentinel
#define SLOTS 10      // bins monotone along k: <=8 changes per 16-elem segment

__global__ __launch_bounds__(256)
void bin_table_kernel(unsigned char* __restrict__ tab, float* __restrict__ g) {
    int v = blockIdx.x * 256 + threadIdx.x;          // 0..262143
    int i = v >> 12, j = (v >> 6) & 63, k = v & 63;
    double xc2 = (double)(j * j + k * k);            // x_comp^2
    double zc2 = (double)(i * i + j * j);            // z_comp^2
    double i2  = (double)(i * i);
    double k2  = (double)(k * k);
    const double T1 = 0.4040262258351568  * 0.4040262258351568;
    const double T2 = 0.9656887748070740  * 0.9656887748070740;
    const double T3 = 2.2460367739042161  * 2.2460367739042161;
    const double T4 = 28.636253282915602  * 28.636253282915602;
    // ax = floor(atan2(xc, i)*deg/22) == #{m : xc^2 > i^2 tan^2(22m)}; strict >
    // handles every atan2 edge case exactly (verified absmax 0.0).
    int ax = (xc2 > i2 * T1) + (xc2 > i2 * T2) + (xc2 > i2 * T3) + (xc2 > i2 * T4);
    int az = (k2 > zc2 * T1) + (k2 > zc2 * T2) + (k2 > zc2 * T3) + (k2 > zc2 * T4);
    tab[v] = (unsigned char)(ax * 16 + az);
    if (v < 32768) g[v] = 0.0f;                      // zero accumulator (ws is poisoned)
}

// Block = (p_lo, i-slab), 4096 blocks, 256 threads. Thread owns j = tid>>2,
// k-segment (tid&3)*16..+15, for BOTH channels pA=p_lo and pB=p_lo+64 (same
// geometry => shared bin/sqrt/cnt chain, two accumulators). Hot loop is
// branch-free & atomic-free: unconditional slot-major LDS writes
// (slotA[s][tid] b64 = (bin,accA), slotB[s][tid] b32 = accB) — lane stride
// 8B/4B => conflict-free. Phase 2 reduces slots -> hist[2][80]; one
// <=160-lane global-atomic flush per block.
__global__ __launch_bounds__(256)
void scatter_kernel(const float4* __restrict__ x4,
                    const uint4* __restrict__ tab4,
                    float* __restrict__ g) {
    __shared__ unsigned long long slotA[SLOTS][256];  // 20 KB
    __shared__ float              slotB[SLOTS][256];  // 10 KB
    __shared__ float hist[2][BINS_PAD];
    int tid = threadIdx.x;
    int pA  = blockIdx.x >> 6;               // 0..63
    int pB  = pA + 64;
    int i   = blockIdx.x & 63;               // i-slab 0..63

    // init own slot columns (sentinel bin=69, acc=+0.0) — own-column only,
    // no pre-phase-1 sync needed
    const unsigned long long SENT = ((unsigned long long)69u) << 32;
    #pragma unroll
    for (int s = 0; s < SLOTS; ++s) { slotA[s][tid] = SENT; slotB[s][tid] = 0.0f; }
    if (tid < 2 * BINS_PAD) ((float*)hist)[tid] = 0.0f;

    int j  = tid >> 2;                       // j-line 0..63
    int k0 = (tid & 3) * 16;                 // k-segment base

    const float4* xsA = x4 + (size_t)pA * 65536 + (size_t)i * 1024;
    const float4* xsB = x4 + (size_t)pB * 65536 + (size_t)i * 1024;
    uint4  tb = tab4[i * 256 + tid];
    float4 xqA[4], xqB[4];
    #pragma unroll
    for (int q = 0; q < 4; ++q) xqA[q] = xsA[4 * tid + q];
    #pragma unroll
    for (int q = 0; q < 4; ++q) xqB[q] = xsB[4 * tid + q];

    float r2f = (float)(i * i + j * j);      // exact (< 2^24)
    unsigned int uq[4] = {tb.x, tb.y, tb.z, tb.w};

    int   cnt  = -1;                         // first element bumps to 0
    int   prev = -1;                         // != any bin => first write slot 0
    float accA = 0.0f, accB = 0.0f;

    #pragma unroll
    for (int q = 0; q < 4; ++q) {
        unsigned int u = uq[q];
        #pragma unroll
        for (int e = 0; e < 4; ++e) {
            float k    = (float)(k0 + 4 * q + e);
            float mag  = sqrtf(fmaf(k, k, r2f));            // shared
            float xeA  = (e == 0) ? xqA[q].x : (e == 1) ? xqA[q].y : (e == 2) ? xqA[q].z : xqA[q].w;
            float xeB  = (e == 0) ? xqB[q].x : (e == 1) ? xqB[q].y : (e == 2) ? xqB[q].z : xqB[q].w;
            float valA = xeA * mag;
            float valB = xeB * mag;
            int   b    = (u >> (8 * e)) & 255;
            bool  ch   = (b != prev);
            cnt += ch ? 1 : 0;
            accA = ch ? valA : (accA + valA);
            accB = ch ? valB : (accB + valB);
            prev = b;
            slotA[cnt][tid] = (((unsigned long long)(unsigned)b) << 32)
                            | (unsigned long long)__float_as_uint(accA);
            slotB[cnt][tid] = accB;
        }
    }
    __syncthreads();

    // phase 2: reduce own slot columns into the block hists
    #pragma unroll
    for (int s = 0; s < SLOTS; ++s) {
        unsigned long long pk = slotA[s][tid];
        float av = __uint_as_float((unsigned int)pk);
        float bv = slotB[s][tid];
        unsigned int bb = (unsigned int)(pk >> 32);       // <= 69 < BINS_PAD
        if (av != 0.0f) atomicAdd(&hist[0][bb], av);
        if (bv != 0.0f) atomicAdd(&hist[1][bb], bv);
    }
    __syncthreads();

    if (tid < BINS_PAD) {
        float hv = hist[0][tid];
        if (hv != 0.0f) atomicAdd(&g[pA * 256 + tid], hv);
    } else if (tid < 2 * BINS_PAD) {
        int b2 = tid - BINS_PAD;
        float hv = hist[1][b2];
        if (hv != 0.0f) atomicAdd(&g[pB * 256 + b2], hv);
    }
}

// Single block: per-channel mean/var over (B, N, N) = 16384 values in double,
// then fused scale/shift write of all 32768 outputs.
__global__ __launch_bounds__(1024)
void norm_kernel(const float* __restrict__ g,
                 const float* __restrict__ gamma,
                 const float* __restrict__ beta,
                 float* __restrict__ out) {
    __shared__ double red[16][4];
    __shared__ float  coef[4];        // sc0, sc1, sh0, sh1
    int t = threadIdx.x;
    float vals[32];
    double s0 = 0.0, s1 = 0.0, q0 = 0.0, q1 = 0.0;
    #pragma unroll
    for (int n = 0; n < 32; ++n) {
        int idx = t + n * 1024;
        float v = g[idx];
        vals[n] = v;
        double vd = (double)v;
        if ((idx >> 8) & 1) { s1 += vd; q1 += vd * vd; }
        else                { s0 += vd; q0 += vd * vd; }
    }
    #pragma unroll
    for (int off = 32; off > 0; off >>= 1) {
        s0 += __shfl_down(s0, off);
        s1 += __shfl_down(s1, off);
        q0 += __shfl_down(q0, off);
        q1 += __shfl_down(q1, off);
    }
    int wave = t >> 6;
    if ((t & 63) == 0) {
        red[wave][0] = s0; red[wave][1] = s1; red[wave][2] = q0; red[wave][3] = q1;
    }
    __syncthreads();
    if (t == 0) {
        double S0 = 0, S1 = 0, Q0 = 0, Q1 = 0;
        for (int wv = 0; wv < 16; ++wv) {
            S0 += red[wv][0]; S1 += red[wv][1]; Q0 += red[wv][2]; Q1 += red[wv][3];
        }
        const double inv_n = 1.0 / 16384.0;
        double m0 = S0 * inv_n, m1 = S1 * inv_n;
        double v0 = Q0 * inv_n - m0 * m0;
        double v1 = Q1 * inv_n - m1 * m1;
        double r0 = 1.0 / sqrt(v0 + 1e-5);
        double r1 = 1.0 / sqrt(v1 + 1e-5);
        float g0 = gamma[0], g1 = gamma[1], b0 = beta[0], b1 = beta[1];
        coef[0] = (float)r0 * g0;
        coef[1] = (float)r1 * g1;
        coef[2] = b0 - (float)(m0 * r0) * g0;
        coef[3] = b1 - (float)(m1 * r1) * g1;
    }
    __syncthreads();
    float sc0 = coef[0], sc1 = coef[1], sh0 = coef[2], sh1 = coef[3];
    #pragma unroll
    for (int n = 0; n < 32; ++n) {
        int idx = t + n * 1024;
        int c = (idx >> 8) & 1;
        out[idx] = vals[n] * (c ? sc1 : sc0) + (c ? sh1 : sh0);
    }
}

extern "C" void kernel_launch(void* const* d_in, const int* in_sizes, int n_in,
                              void* d_out, int out_size, void* d_ws, size_t ws_size,
                              hipStream_t stream) {
    const float* x     = (const float*)d_in[0];
    const float* gamma = (const float*)d_in[1];
    const float* beta  = (const float*)d_in[2];
    float* out = (float*)d_out;

    unsigned char* tab = (unsigned char*)d_ws;
    float*         g   = (float*)((char*)d_ws + 262144);

    bin_table_kernel<<<1024, 256, 0, stream>>>(tab, g);
    scatter_kernel<<<4096, 256, 0, stream>>>((const float4*)x, (const uint4*)tab, g);
    norm_kernel<<<1, 1024, 0, stream>>>(g, gamma, beta, out);
}